// Round 1
// baseline (899.412 us; speedup 1.0000x reference)
//
#include <hip/hip_runtime.h>
#include <hip/hip_bf16.h>

#define N_PTS 262144
#define STEP_LEN 0.0016914558667664818f

using f32x4 = __attribute__((ext_vector_type(4))) float;
using s8 = __attribute__((ext_vector_type(8))) short;

__device__ __forceinline__ float bf2f(short s) {
    union { unsigned int u; float f; } v;
    v.u = ((unsigned int)(unsigned short)s) << 16;
    return v.f;
}

// ---- workspace (bf16 padded weights) layout, in elements ----
#define OFF_W1   0          // [256][64]   (63 -> 64 pad)
#define OFF_W1H  16384      // [3][256][256]
#define OFF_W2   212992     // [256][320]  (319 -> 320 pad)
#define OFF_W2H  294912     // [3][256][256]
#define OFF_WC1  491520     // [128][320]  (283 -> 320 pad)
#define WS_ELEMS 532480

__global__ void prep_weights(const float* __restrict__ w1_in,
                             const float* __restrict__ w1_h,
                             const float* __restrict__ w2_in,
                             const float* __restrict__ w2_h,
                             const float* __restrict__ w_c1,
                             __hip_bfloat16* __restrict__ ws) {
    int i = blockIdx.x * blockDim.x + threadIdx.x;
    if (i >= WS_ELEMS) return;
    float v;
    if (i < OFF_W1H) {
        int j = i - OFF_W1; int r = j >> 6, c = j & 63;
        v = (c < 63) ? w1_in[r * 63 + c] : 0.f;
    } else if (i < OFF_W2) {
        v = w1_h[i - OFF_W1H];
    } else if (i < OFF_W2H) {
        int j = i - OFF_W2; int r = j / 320, c = j % 320;
        v = (c < 319) ? w2_in[r * 319 + c] : 0.f;
    } else if (i < OFF_WC1) {
        v = w2_h[i - OFF_W2H];
    } else {
        int j = i - OFF_WC1; int r = j / 320, c = j % 320;
        v = (c < 283) ? w_c1[r * 283 + c] : 0.f;
    }
    ws[i] = __float2bfloat16(v);
}

// One layer GEMM tile: out[128 x Ncols] = relu(in[128 x K] * W^T + bias)
// Wave (wm,wn) computes rows [wm*64, wm*64+64) x cols [n0, n0+16*NT).
// LDS in/out are bf16, row-major with byte stride inStride/outStride,
// XOR-swizzled: byte ^= (row&7)<<4.  W is bf16 [*, Kpad] row-major in global.
template<int NT>
__device__ __forceinline__ void gemm_layer(
    const char* inB, int inStride, int ksteps,
    const __hip_bfloat16* __restrict__ W, int Kpad,
    const float* __restrict__ bias,
    char* outB, int outStride,
    int m0, int n0, int lane) {

    const int rlo = lane & 15;        // A row / B col within 16
    const int khi = (lane >> 4) << 3; // k sub-offset (8 contiguous)

    f32x4 acc[4][NT];
#pragma unroll
    for (int mt = 0; mt < 4; ++mt)
#pragma unroll
        for (int nt = 0; nt < NT; ++nt)
            acc[mt][nt] = f32x4{0.f, 0.f, 0.f, 0.f};

    int arow[4], abase[4];
#pragma unroll
    for (int mt = 0; mt < 4; ++mt) {
        arow[mt] = m0 + mt * 16 + rlo;
        abase[mt] = arow[mt] * inStride;
    }
    const __hip_bfloat16* wrow[NT];
#pragma unroll
    for (int nt = 0; nt < NT; ++nt) {
        int n = n0 + nt * 16 + rlo;
        wrow[nt] = W + n * Kpad + khi;
    }

    s8 aA[4], bA[NT], aB[4], bB[NT];

    auto loadA = [&](int ks, s8* af) {
#pragma unroll
        for (int mt = 0; mt < 4; ++mt) {
            int byt = abase[mt] + (ks * 32 + khi) * 2;
            af[mt] = *(const s8*)(inB + (byt ^ ((arow[mt] & 7) << 4)));
        }
    };
    auto loadB = [&](int ks, s8* bf) {
#pragma unroll
        for (int nt = 0; nt < NT; ++nt)
            bf[nt] = *(const s8*)(wrow[nt] + ks * 32);
    };
    auto mm = [&](s8* af, s8* bf) {
#pragma unroll
        for (int mt = 0; mt < 4; ++mt)
#pragma unroll
            for (int nt = 0; nt < NT; ++nt)
                acc[mt][nt] = __builtin_amdgcn_mfma_f32_16x16x32_bf16(
                    af[mt], bf[nt], acc[mt][nt], 0, 0, 0);
    };

    loadA(0, aA); loadB(0, bA);
    for (int ks = 0; ks < ksteps; ks += 2) {
        if (ks + 1 < ksteps) { loadA(ks + 1, aB); loadB(ks + 1, bB); }
        mm(aA, bA);
        if (ks + 2 < ksteps) { loadA(ks + 2, aA); loadB(ks + 2, bA); }
        if (ks + 1 < ksteps) mm(aB, bB);
    }

    // epilogue: bias + relu + bf16 -> LDS (C/D: col=lane&15, row=(lane>>4)*4+r)
    const int rhi = (lane >> 4) << 2;
#pragma unroll
    for (int nt = 0; nt < NT; ++nt) {
        int n = n0 + nt * 16 + rlo;
        float bv = bias[n];
#pragma unroll
        for (int mt = 0; mt < 4; ++mt) {
            f32x4 v = acc[mt][nt];
#pragma unroll
            for (int r = 0; r < 4; ++r) {
                int row = m0 + mt * 16 + rhi + r;
                float x = fmaxf(v[r] + bv, 0.f);
                int byt = row * outStride + n * 2;
                *(__hip_bfloat16*)(outB + (byt ^ ((row & 7) << 4))) =
                    __float2bfloat16(x);
            }
        }
    }
}

__global__ __launch_bounds__(512, 2) void nerf_fused(
    const float* __restrict__ pos, const float* __restrict__ dir,
    const __hip_bfloat16* __restrict__ ws,
    const float* __restrict__ b1_in, const float* __restrict__ b1_h,
    const float* __restrict__ b2_in, const float* __restrict__ b2_h,
    const float* __restrict__ w_sigma, const float* __restrict__ b_sigma,
    const float* __restrict__ b_c1,
    const float* __restrict__ w_c2, const float* __restrict__ b_c2,
    float* __restrict__ out) {

    // sCat: [128][320] bf16 — cols 0..255 = activations, 256..319 = pe / (de|sigma|0)
    // sX:   [128][256] bf16 — ping-pong buffer
    __shared__ __align__(16) __hip_bfloat16 sCat[128 * 320];
    __shared__ __align__(16) __hip_bfloat16 sX[128 * 256];
    __shared__ float sraw[128];

    const int t = threadIdx.x;
    const int lane = t & 63;
    const int wid = t >> 6;
    const int wm = wid >> 2, wn = wid & 3;
    const int m0 = wm * 64;
    const int row0 = blockIdx.x * 128;

    char* catB = (char*)sCat;
    char* xB = (char*)sX;

    // ---- phase 0: positional encoding -> sCat cols 256..319 (63 + zero pad)
    {
        int r = t >> 2, p = t & 3;
        int g = row0 + r;
        float x0 = pos[g * 3 + 0], x1 = pos[g * 3 + 1], x2 = pos[g * 3 + 2];
        for (int e = p; e < 64; e += 4) {
            float v;
            if (e < 3) {
                v = (e == 0) ? x0 : ((e == 1) ? x1 : x2);
            } else if (e < 33) {
                int j = e - 3; int c = j / 10, f = j % 10;
                float xc = (c == 0) ? x0 : ((c == 1) ? x1 : x2);
                v = sinf(xc * (float)(1 << f));
            } else if (e < 63) {
                int j = e - 33; int c = j / 10, f = j % 10;
                float xc = (c == 0) ? x0 : ((c == 1) ? x1 : x2);
                v = cosf(xc * (float)(1 << f));
            } else {
                v = 0.f;
            }
            int byt = r * 640 + (256 + e) * 2;
            *(__hip_bfloat16*)(catB + (byt ^ ((r & 7) << 4))) = __float2bfloat16(v);
        }
    }
    __syncthreads();

    // ---- base_mlp_1
    // L1_in: pe (K=64, at byte offset 512 in each sCat row) -> sX
    gemm_layer<4>(catB + 512, 640, 2, ws + OFF_W1, 64, b1_in, xB, 512, m0, wn * 64, lane);
    __syncthreads();
    gemm_layer<4>(xB, 512, 8, ws + OFF_W1H + 0 * 65536, 256, b1_h + 0 * 256, catB, 640, m0, wn * 64, lane);
    __syncthreads();
    gemm_layer<4>(catB, 640, 8, ws + OFF_W1H + 1 * 65536, 256, b1_h + 1 * 256, xB, 512, m0, wn * 64, lane);
    __syncthreads();
    gemm_layer<4>(xB, 512, 8, ws + OFF_W1H + 2 * 65536, 256, b1_h + 2 * 256, catB, 640, m0, wn * 64, lane);
    __syncthreads();
    // sCat now holds [h(256) | pe(63) | 0] per row.

    // ---- base_mlp_2
    gemm_layer<4>(catB, 640, 10, ws + OFF_W2, 320, b2_in, xB, 512, m0, wn * 64, lane);
    __syncthreads();
    gemm_layer<4>(xB, 512, 8, ws + OFF_W2H + 0 * 65536, 256, b2_h + 0 * 256, catB, 640, m0, wn * 64, lane);
    __syncthreads();
    gemm_layer<4>(catB, 640, 8, ws + OFF_W2H + 1 * 65536, 256, b2_h + 1 * 256, xB, 512, m0, wn * 64, lane);
    __syncthreads();
    gemm_layer<4>(xB, 512, 8, ws + OFF_W2H + 2 * 65536, 256, b2_h + 2 * 256, catB, 640, m0, wn * 64, lane);
    __syncthreads();
    // g in sCat cols 0..255

    // ---- sigma head + alpha output
    {
        int r = t >> 2, p = t & 3;
        float acc = 0.f;
        int kb = p * 64;
        for (int kk = 0; kk < 8; ++kk) {
            int k = kb + kk * 8;
            int byt = r * 640 + k * 2;
            s8 v = *(const s8*)(catB + (byt ^ ((r & 7) << 4)));
#pragma unroll
            for (int j = 0; j < 8; ++j) acc += bf2f(v[j]) * w_sigma[k + j];
        }
        acc += __shfl_xor(acc, 1);
        acc += __shfl_xor(acc, 2);
        float sr = acc + b_sigma[0];
        if (p == 0) {
            sraw[r] = sr;
            out[3 * N_PTS + row0 + r] = 1.f - expf(-fmaxf(sr, 0.f) * STEP_LEN);
        }
    }
    __syncthreads();

    // ---- dir encoding + sigma feature + zero pad -> sCat cols 256..319
    {
        int r = t >> 2, p = t & 3;
        int g = row0 + r;
        float u0 = (dir[g * 3 + 0] + 1.f) * 0.5f;
        float u1 = (dir[g * 3 + 1] + 1.f) * 0.5f;
        float u2 = (dir[g * 3 + 2] + 1.f) * 0.5f;
        for (int e = p; e < 64; e += 4) {
            float v;
            if (e < 13) {
                int c = e / 5, f = e % 5;
                float uc = (c == 0) ? u0 : ((c == 1) ? u1 : u2);
                v = sinf(uc * (float)(1 << f));
            } else if (e < 26) {
                int j = e - 13; int c = j / 5, f = j % 5;
                float uc = (c == 0) ? u0 : ((c == 1) ? u1 : u2);
                v = cosf(uc * (float)(1 << f));
            } else if (e == 26) {
                v = sraw[r];
            } else {
                v = 0.f;
            }
            int byt = r * 640 + (256 + e) * 2;
            *(__hip_bfloat16*)(catB + (byt ^ ((r & 7) << 4))) = __float2bfloat16(v);
        }
    }
    __syncthreads();

    // ---- color layer 1: [g|de|sigma|0] (K=320) -> 128 cols, relu -> sX
    gemm_layer<2>(catB, 640, 10, ws + OFF_WC1, 320, b_c1, xB, 512, m0, wn * 32, lane);
    __syncthreads();

    // ---- color layer 2 + sigmoid -> rgb output
    {
        int r = t >> 2, p = t & 3;
        float a0 = 0.f, a1 = 0.f, a2 = 0.f;
        int kb = p * 32;
        for (int kk = 0; kk < 4; ++kk) {
            int k = kb + kk * 8;
            int byt = r * 512 + k * 2;
            s8 v = *(const s8*)(xB + (byt ^ ((r & 7) << 4)));
#pragma unroll
            for (int j = 0; j < 8; ++j) {
                float f = bf2f(v[j]);
                a0 += f * w_c2[0 * 128 + k + j];
                a1 += f * w_c2[1 * 128 + k + j];
                a2 += f * w_c2[2 * 128 + k + j];
            }
        }
        a0 += __shfl_xor(a0, 1); a0 += __shfl_xor(a0, 2);
        a1 += __shfl_xor(a1, 1); a1 += __shfl_xor(a1, 2);
        a2 += __shfl_xor(a2, 1); a2 += __shfl_xor(a2, 2);
        if (p == 0) {
            int o = (row0 + r) * 3;
            out[o + 0] = 1.f / (1.f + expf(-(a0 + b_c2[0])));
            out[o + 1] = 1.f / (1.f + expf(-(a1 + b_c2[1])));
            out[o + 2] = 1.f / (1.f + expf(-(a2 + b_c2[2])));
        }
    }
}

extern "C" void kernel_launch(void* const* d_in, const int* in_sizes, int n_in,
                              void* d_out, int out_size, void* d_ws, size_t ws_size,
                              hipStream_t stream) {
    const float* position = (const float*)d_in[0];
    const float* direction = (const float*)d_in[1];
    const float* w1_in = (const float*)d_in[2];
    const float* b1_in = (const float*)d_in[3];
    const float* w1_h  = (const float*)d_in[4];
    const float* b1_h  = (const float*)d_in[5];
    const float* w2_in = (const float*)d_in[6];
    const float* b2_in = (const float*)d_in[7];
    const float* w2_h  = (const float*)d_in[8];
    const float* b2_h  = (const float*)d_in[9];
    const float* w_sigma = (const float*)d_in[10];
    const float* b_sigma = (const float*)d_in[11];
    const float* w_c1  = (const float*)d_in[12];
    const float* b_c1  = (const float*)d_in[13];
    const float* w_c2  = (const float*)d_in[14];
    const float* b_c2  = (const float*)d_in[15];
    float* out = (float*)d_out;
    __hip_bfloat16* ws = (__hip_bfloat16*)d_ws;

    prep_weights<<<(WS_ELEMS + 255) / 256, 256, 0, stream>>>(
        w1_in, w1_h, w2_in, w2_h, w_c1, ws);

    nerf_fused<<<N_PTS / 128, 512, 0, stream>>>(
        position, direction, ws,
        b1_in, b1_h, b2_in, b2_h,
        w_sigma, b_sigma, b_c1, w_c2, b_c2, out);
}